// Round 11
// baseline (78.304 us; speedup 1.0000x reference)
//
#include <hip/hip_runtime.h>

// CircleLoss, B=8192, D=128, fp32 in, scalar fp32 out.
// Pipeline: (1) normalize->bf16 + fused diagonal dot, (2) fused bf16-MFMA
// sim GEMM + masked-LSE partials -- ZERO LDS / ZERO BARRIERS: A and B
// fragments load directly global->VGPR (L1/L2-resident), waves free-run,
// (3) rowfin, (4) mean.

#define B_N 8192
#define D_K 128
#define MARGIN 0.25f
#define M2 (MARGIN * MARGIN)
#define GAMMA 256.0f

#define BM 128          // rows per block (A panel)
#define BN 64           // cols per subtile
#define NCH 16          // column chunks
#define CPB (B_N / NCH) // 512 columns per chunk
#define NSUB (CPB / BN) // 8 subtiles per chunk
#define NROWBLK 32      // rowfin blocks

typedef __attribute__((ext_vector_type(8))) short short8;
typedef __attribute__((ext_vector_type(4))) float f32x4;

__device__ __forceinline__ unsigned short f2bf(float x) {
  // round-to-nearest-even fp32 -> bf16
  unsigned u = __float_as_uint(x);
  u += 0x7FFFu + ((u >> 16) & 1u);
  return (unsigned short)(u >> 16);
}

// ------- kernel 1: L2-normalize rows -> bf16, plus diagonal dot -------
// One wave per row index r: lanes 0-31 handle a[r], lanes 32-63 handle b[r]
// (float4 each). After normalize, cross-half shfl gives diag[r]=dot(a_n,b_n).
__global__ __launch_bounds__(256) void norm_diag_kernel(
    const float* __restrict__ a, const float* __restrict__ b,
    unsigned short* __restrict__ abf, unsigned short* __restrict__ bbf,
    float* __restrict__ diag) {
  int wave = threadIdx.x >> 6, lane = threadIdx.x & 63;
  int r = blockIdx.x * 4 + wave;  // 0..B_N-1
  int half = lane >> 5, l32 = lane & 31;
  const float* src = half ? b : a;
  unsigned short* dst = half ? bbf : abf;

  float4 v = ((const float4*)(src + (size_t)r * D_K))[l32];
  float ss = v.x * v.x + v.y * v.y + v.z * v.z + v.w * v.w;
  #pragma unroll
  for (int m = 16; m >= 1; m >>= 1) ss += __shfl_xor(ss, m);  // within half
  float inv = 1.0f / fmaxf(sqrtf(ss), 1e-12f);
  float n0 = v.x * inv, n1 = v.y * inv, n2 = v.z * inv, n3 = v.w * inv;

  ushort4 o = {f2bf(n0), f2bf(n1), f2bf(n2), f2bf(n3)};
  ((ushort4*)(dst + (size_t)r * D_K))[l32] = o;

  // diagonal dot: pair with same l32 in the other half
  float d = n0 * __shfl_xor(n0, 32) + n1 * __shfl_xor(n1, 32) +
            n2 * __shfl_xor(n2, 32) + n3 * __shfl_xor(n3, 32);
  #pragma unroll
  for (int m = 16; m >= 1; m >>= 1) d += __shfl_xor(d, m);
  if (lane == 0) diag[r] = d;
}

// ---------- kernel 2: fused sim GEMM (bf16 MFMA) + neg-LSE partials ----------
// grid = 1024 blocks (1D, XCD-swizzled: 8 XCDs x 2 chunks x 64 row-blocks),
// block = 256 (4 waves; each wave owns a 32-row strip across the full chunk,
// iterating 8 subtiles of 64 cols as 2x4 fragments of 16x16).
// NO LDS, NO BARRIERS: A-frags and B-frags load directly global->VGPR.
// Per bf load the 64 lanes read 16 rows x 64 contiguous B = 16 fully-used
// cache lines; B chunk (128KB) is L1/L2-hot and shared by the block's waves.
// Epilogue accumulates sum(exp(logit_neg)-1): zero for reg-quads with all
// s<=m (uniform __any skip). Diagonal handled in kernels 1/3.
__global__ __launch_bounds__(256, 4) void simlse_kernel(
    const unsigned short* __restrict__ abf, const unsigned short* __restrict__ bbf,
    float* __restrict__ partS) {
  const int tid = threadIdx.x;
  const int wave = tid >> 6, lane = tid & 63;
  const int r16 = lane & 15, kq = lane >> 4;

  // XCD-aware mapping: xcd = bid%8 (round-robin dispatch heuristic);
  // each XCD owns 2 column-chunks -> its L2 holds 256KB of B + 2MB of A.
  const int bid = blockIdx.x;
  const int xcd = bid & 7, lid = bid >> 3;         // lid 0..127
  const int chunk = xcd * 2 + (lid >> 6);          // 0..15
  const int rowBase = (lid & 63) * BM;             // 0..8064

  // A-fragments direct global->reg (one-time; 16 fully-used lines per load)
  short8 af[2][4];  // [mi][ks]
  #pragma unroll
  for (int mi = 0; mi < 2; ++mi) {
    const unsigned short* arow =
        abf + (size_t)(rowBase + wave * 32 + mi * 16 + r16) * D_K;
    #pragma unroll
    for (int ks = 0; ks < 4; ++ks)
      af[mi][ks] = *(const short8*)&arow[(ks * 4 + kq) * 8];
  }

  // per-lane B row pointers; advance one subtile (BN rows) per st
  const unsigned short* bptr[4];
  #pragma unroll
  for (int ni = 0; ni < 4; ++ni)
    bptr[ni] = bbf + (size_t)(chunk * CPB + ni * 16 + r16) * D_K + kq * 8;

  float Ssum[2][4];  // [mi][reg] per-row running sum of (exp(logit_neg)-1)
  #pragma unroll
  for (int mi = 0; mi < 2; ++mi)
    #pragma unroll
    for (int r = 0; r < 4; ++r) Ssum[mi][r] = 0.0f;

  #pragma unroll 2
  for (int st = 0; st < NSUB; ++st) {
    f32x4 acc[2][4];
    const f32x4 z4 = {0.f, 0.f, 0.f, 0.f};
    #pragma unroll
    for (int mi = 0; mi < 2; ++mi)
      #pragma unroll
      for (int ni = 0; ni < 4; ++ni) acc[mi][ni] = z4;

    #pragma unroll
    for (int ks = 0; ks < 4; ++ks) {
      short8 bf[4];
      #pragma unroll
      for (int ni = 0; ni < 4; ++ni)
        bf[ni] = *(const short8*)(bptr[ni] + ks * 32);
      #pragma unroll
      for (int mi = 0; mi < 2; ++mi)
        #pragma unroll
        for (int ni = 0; ni < 4; ++ni)
          acc[mi][ni] = __builtin_amdgcn_mfma_f32_16x16x32_bf16(
              af[mi][ks], bf[ni], acc[mi][ni], 0, 0, 0);
    }

    // epilogue: logit = (s>m) ? GAMMA*(s^2-m^2) : 0; accumulate exp(logit)-1.
    // For unit-normal embeddings P(s>m) ~ 0.2%, so most reg-quads skip.
    #pragma unroll
    for (int mi = 0; mi < 2; ++mi)
      #pragma unroll
      for (int ni = 0; ni < 4; ++ni) {
        f32x4 v = acc[mi][ni];
        float mx = fmaxf(fmaxf(v[0], v[1]), fmaxf(v[2], v[3]));
        if (__any(mx > MARGIN)) {
          #pragma unroll
          for (int r = 0; r < 4; ++r) {
            float s = v[r];
            float t = fmaf(s, s, -M2);
            float z = (s > MARGIN) ? GAMMA * t : 0.0f;
            Ssum[mi][r] += __expf(z) - 1.0f;  // exactly 0 when z==0
          }
        }
      }

    #pragma unroll
    for (int ni = 0; ni < 4; ++ni) bptr[ni] += BN * D_K;
  }

  // each wave owns its 32 rows across the full chunk width -> reduce over
  // the 16 column-lanes (same kq group) and write partS directly.
  #pragma unroll
  for (int mi = 0; mi < 2; ++mi)
    #pragma unroll
    for (int r = 0; r < 4; ++r) {
      float v = Ssum[mi][r];
      v += __shfl_xor(v, 1);
      v += __shfl_xor(v, 2);
      v += __shfl_xor(v, 4);
      v += __shfl_xor(v, 8);
      if (r16 == 0)
        partS[(size_t)chunk * B_N + rowBase + wave * 32 + mi * 16 + kq * 4 + r] = v;
    }
}

// ------- kernel 3: per-row finalize + per-block partial sum -------
__global__ __launch_bounds__(256) void rowfin_kernel(
    const float* __restrict__ partS, const float* __restrict__ diag,
    float* __restrict__ bpart) {
  __shared__ float red[4];
  int tid = threadIdx.x, lane = tid & 63, wid = tid >> 6;
  int i = blockIdx.x * 256 + tid;
  float S = 0.0f;
  #pragma unroll
  for (int c = 0; c < NCH; ++c) S += partS[(size_t)c * B_N + i];
  float sd = diag[i];
  float zd = (sd > MARGIN) ? GAMMA * fmaf(sd, sd, -M2) : 0.0f;
  float ed = __expf(zd);
  // sum over off-diagonal of exp(logit_neg) = B + sum(e-1 over all) - e_diag
  float lneg = __logf((float)B_N + S - ed);
  float lpos = -GAMMA * fmaxf((1.0f - MARGIN) - sd, 0.0f) * (sd - MARGIN);
  float x = lpos + lneg;
  float acc = fmaxf(x, 0.0f) + log1pf(__expf(-fabsf(x)));  // softplus
  #pragma unroll
  for (int m = 32; m >= 1; m >>= 1) acc += __shfl_xor(acc, m);
  if (lane == 0) red[wid] = acc;
  __syncthreads();
  if (tid == 0) bpart[blockIdx.x] = red[0] + red[1] + red[2] + red[3];
}

// ---------------- kernel 4: mean over 32 block partials ----------------
__global__ __launch_bounds__(64) void mean_kernel(
    const float* __restrict__ bpart, float* __restrict__ out) {
  int lane = threadIdx.x;
  float v = (lane < 32) ? bpart[lane] : 0.0f;
  #pragma unroll
  for (int m = 32; m >= 1; m >>= 1) v += __shfl_xor(v, m);
  if (lane == 0) out[0] = v * (1.0f / B_N);
}

extern "C" void kernel_launch(void* const* d_in, const int* in_sizes, int n_in,
                              void* d_out, int out_size, void* d_ws, size_t ws_size,
                              hipStream_t stream) {
  const float* a = (const float*)d_in[0];
  const float* b = (const float*)d_in[1];
  float* out = (float*)d_out;

  char* w = (char*)d_ws;
  unsigned short* abf = (unsigned short*)w;                              // 2 MB
  unsigned short* bbf = (unsigned short*)(w + (size_t)B_N * D_K * 2);    // 2 MB
  float* partS = (float*)(w + (size_t)B_N * D_K * 4);                    // 512 KB
  float* diag = partS + (size_t)NCH * B_N;                               // 32 KB
  float* bpart = diag + B_N;                                             // 128 B

  norm_diag_kernel<<<B_N / 4, 256, 0, stream>>>(a, b, abf, bbf, diag);
  simlse_kernel<<<NCH * (B_N / BM), 256, 0, stream>>>(abf, bbf, partS);
  rowfin_kernel<<<NROWBLK, 256, 0, stream>>>(partS, diag, bpart);
  mean_kernel<<<1, 64, 0, stream>>>(bpart, out);
}